// Round 1
// baseline (1067.687 us; speedup 1.0000x reference)
//
#include <hip/hip_runtime.h>

#define C 128
#define NC 25000
#define ROWS 16

// out[dst[e]] += attr[e] * in[src[e]]  (C channels per edge)
// 4 edges per 512-thread block; thread -> (edge_in_block, channel)
__global__ __launch_bounds__(512) void scatter_add_k(
    const float* __restrict__ in, const int* __restrict__ src,
    const int* __restrict__ dst, const float* __restrict__ attr,
    float* __restrict__ out, int nE) {
    int e = blockIdx.x * 4 + (threadIdx.x >> 7);
    if (e >= nE) return;
    int c = threadIdx.x & 127;
    int s = src[e], d = dst[e];
    float a = attr[e];
    atomicAdd(&out[(size_t)d * C + c], a * in[(size_t)s * C + c]);
}

// h[i] = relu(h[i] @ ws + agg[i] @ wn + b), in-place over a ROWS-row tile.
__global__ __launch_bounds__(256) void conv_gemm_k(
    float* __restrict__ h, const float* __restrict__ agg,
    const float* __restrict__ ws, const float* __restrict__ wn,
    const float* __restrict__ b, int n) {
    __shared__ float hs[ROWS][C];
    __shared__ float as[ROWS][C];
    const int r0 = blockIdx.x * ROWS;
    const int tid = threadIdx.x;

    // stage tile: 2048 elems per array, 256 threads -> 8 each
    for (int i = tid; i < ROWS * C; i += 256) {
        int r = i >> 7, c = i & 127;
        int gr = r0 + r;
        float hv = 0.f, av = 0.f;
        if (gr < n) {
            hv = h[(size_t)gr * C + c];
            av = agg[(size_t)gr * C + c];
        }
        hs[r][c] = hv;
        as[r][c] = av;
    }
    __syncthreads();

    const int c = tid & 127;
    const int rhalf = tid >> 7;  // 0 or 1: which 8-row half this thread owns
    float acc[ROWS / 2];
#pragma unroll
    for (int j = 0; j < ROWS / 2; ++j) acc[j] = 0.f;

    for (int k = 0; k < C; ++k) {
        float wsk = ws[k * C + c];
        float wnk = wn[k * C + c];
#pragma unroll
        for (int j = 0; j < ROWS / 2; ++j) {
            int r = rhalf * (ROWS / 2) + j;
            acc[j] = fmaf(hs[r][k], wsk, acc[j]);  // LDS broadcast (uniform addr/wave)
            acc[j] = fmaf(as[r][k], wnk, acc[j]);
        }
    }

    float bias = b[c];
#pragma unroll
    for (int j = 0; j < ROWS / 2; ++j) {
        int r = rhalf * (ROWS / 2) + j;
        int gr = r0 + r;
        if (gr < n) {
            float v = acc[j] + bias;
            h[(size_t)gr * C + c] = v > 0.f ? v : 0.f;
        }
    }
}

extern "C" void kernel_launch(void* const* d_in, const int* in_sizes, int n_in,
                              void* d_out, int out_size, void* d_ws, size_t ws_size,
                              hipStream_t stream) {
    const float* x         = (const float*)d_in[0];
    const int*   pool_src  = (const int*)d_in[1];
    const int*   pool_dst  = (const int*)d_in[2];
    const float* pool_attr = (const float*)d_in[3];
    const int*   pp_src    = (const int*)d_in[4];
    const int*   pp_dst    = (const int*)d_in[5];
    const float* pp_attr   = (const float*)d_in[6];
    const int*   up_src    = (const int*)d_in[7];
    const int*   up_dst    = (const int*)d_in[8];
    const float* up_attr   = (const float*)d_in[9];
    const float* w[12];
    for (int i = 0; i < 12; ++i) w[i] = (const float*)d_in[10 + i];

    const int E_pool = in_sizes[1];
    const int E_pp   = in_sizes[4];
    const int E_up   = in_sizes[7];
    const int n_fine = in_sizes[0] / C;   // 100000
    const int n_coarse = NC;              // 25000 (fixed by problem instance)

    float* h   = (float*)d_ws;                       // [n_coarse, C]
    float* agg = h + (size_t)n_coarse * C;           // [n_coarse, C]
    float* out = (float*)d_out;                      // [n_fine, C]

    const size_t hbytes = (size_t)n_coarse * C * sizeof(float);

    // 1. pool: h = segsum(pool_attr * x[pool_src] -> pool_dst)
    hipMemsetAsync(h, 0, hbytes, stream);
    scatter_add_k<<<(E_pool + 3) / 4, 512, 0, stream>>>(
        x, pool_src, pool_dst, pool_attr, h, E_pool);

    // 2. four conv layers
    for (int l = 0; l < 4; ++l) {
        hipMemsetAsync(agg, 0, hbytes, stream);
        scatter_add_k<<<(E_pp + 3) / 4, 512, 0, stream>>>(
            h, pp_src, pp_dst, pp_attr, agg, E_pp);
        conv_gemm_k<<<(n_coarse + ROWS - 1) / ROWS, 256, 0, stream>>>(
            h, agg, w[3 * l], w[3 * l + 1], w[3 * l + 2], n_coarse);
    }

    // 3. unpool: out = segsum(up_attr * h[up_src] -> up_dst)
    hipMemsetAsync(out, 0, (size_t)n_fine * C * sizeof(float), stream);
    scatter_add_k<<<(E_up + 3) / 4, 512, 0, stream>>>(
        h, up_src, up_dst, up_attr, out, E_up);
}

// Round 2
// 606.220 us; speedup vs baseline: 1.7612x; 1.7612x over previous
//
#include <hip/hip_runtime.h>

#define C 128
#define NC 25000

// ---------------- CSR build ----------------

__global__ void hist_k(const int* __restrict__ dst, int* __restrict__ cnt, int nE) {
    int i = blockIdx.x * blockDim.x + threadIdx.x;
    if (i < nE) atomicAdd(&cnt[dst[i]], 1);
}

// Exclusive scan of cnt[0..n) -> off[0..n], single 1024-thread block,
// 4096 elements/chunk, wave-shuffle scan (3 barriers per chunk).
__global__ __launch_bounds__(1024) void scan_k(const int* __restrict__ cnt,
                                               int* __restrict__ off, int n) {
    __shared__ int wsum[16];
    __shared__ int s_carry;
    const int tid = threadIdx.x;
    const int lane = tid & 63;
    const int wid = tid >> 6;
    if (tid == 0) s_carry = 0;
    __syncthreads();
    for (int base = 0; base < n; base += 4096) {
        int carry = s_carry;
        int idx0 = base + tid * 4;
        int v[4];
        int s = 0;
#pragma unroll
        for (int j = 0; j < 4; ++j) {
            v[j] = (idx0 + j < n) ? cnt[idx0 + j] : 0;
            s += v[j];
        }
        // inclusive scan of s within wave
        int sc = s;
#pragma unroll
        for (int d = 1; d < 64; d <<= 1) {
            int t = __shfl_up(sc, d, 64);
            if (lane >= d) sc += t;
        }
        if (lane == 63) wsum[wid] = sc;
        __syncthreads();
        if (wid == 0) {
            int ws = (lane < 16) ? wsum[lane] : 0;
#pragma unroll
            for (int d = 1; d < 16; d <<= 1) {
                int t = __shfl_up(ws, d, 64);
                if (lane >= d) ws += t;
            }
            if (lane < 16) wsum[lane] = ws;
        }
        __syncthreads();
        int wave_off = (wid > 0) ? wsum[wid - 1] : 0;
        int excl = carry + wave_off + sc - s;
#pragma unroll
        for (int j = 0; j < 4; ++j) {
            if (idx0 + j < n) off[idx0 + j] = excl;
            excl += v[j];
        }
        __syncthreads();
        if (tid == 0) s_carry = carry + wsum[15];
        __syncthreads();
    }
    if (tid == 0) off[n] = s_carry;
}

__global__ void fill_k(const int* __restrict__ src, const int* __restrict__ dst,
                       const float* __restrict__ attr, const int* __restrict__ off,
                       int* __restrict__ cur, int* __restrict__ ssrc,
                       float* __restrict__ sattr, int nE) {
    int i = blockIdx.x * blockDim.x + threadIdx.x;
    if (i < nE) {
        int d = dst[i];
        int p = atomicAdd(&cur[d], 1);
        int slot = off[d] + p;
        ssrc[slot] = src[i];
        sattr[slot] = attr[i];
    }
}

// ---------------- CSR gather: out[i] = sum_e attr[e] * in[src[e]] ----------------
// One wave per node, lane = 2 channels (float2). 4 nodes per 256-block.
__global__ __launch_bounds__(256) void gather_k(
    const float* __restrict__ in, const int* __restrict__ off,
    const int* __restrict__ ssrc, const float* __restrict__ sattr,
    float* __restrict__ out, int n) {
    int node = blockIdx.x * 4 + (threadIdx.x >> 6);
    if (node >= n) return;
    int lane = threadIdx.x & 63;
    int e0 = off[node], e1 = off[node + 1];
    const float2* in2 = (const float2*)in;
    float2 acc = make_float2(0.f, 0.f);
    int e = e0;
    for (; e + 1 < e1; e += 2) {
        int s0 = ssrc[e], s1 = ssrc[e + 1];
        float a0 = sattr[e], a1 = sattr[e + 1];
        float2 v0 = in2[(size_t)s0 * 64 + lane];
        float2 v1 = in2[(size_t)s1 * 64 + lane];
        acc.x = fmaf(a0, v0.x, acc.x);
        acc.y = fmaf(a0, v0.y, acc.y);
        acc.x = fmaf(a1, v1.x, acc.x);
        acc.y = fmaf(a1, v1.y, acc.y);
    }
    if (e < e1) {
        int s0 = ssrc[e];
        float a0 = sattr[e];
        float2 v0 = in2[(size_t)s0 * 64 + lane];
        acc.x = fmaf(a0, v0.x, acc.x);
        acc.y = fmaf(a0, v0.y, acc.y);
    }
    ((float2*)out)[(size_t)node * 64 + lane] = acc;
}

// ---------------- fused conv GEMM: h = relu(h@ws + agg@wn + b), in-place ----------------
#define ROWS 16
__global__ __launch_bounds__(256) void conv_gemm_k(
    float* __restrict__ h, const float* __restrict__ agg,
    const float* __restrict__ ws, const float* __restrict__ wn,
    const float* __restrict__ b, int n) {
    __shared__ float hs[ROWS][C];
    __shared__ float as[ROWS][C];
    const int r0 = blockIdx.x * ROWS;
    const int tid = threadIdx.x;

    for (int i = tid; i < ROWS * C; i += 256) {
        int r = i >> 7, c = i & 127;
        int gr = r0 + r;
        float hv = 0.f, av = 0.f;
        if (gr < n) {
            hv = h[(size_t)gr * C + c];
            av = agg[(size_t)gr * C + c];
        }
        hs[r][c] = hv;
        as[r][c] = av;
    }
    __syncthreads();

    const int c = tid & 127;
    const int rhalf = tid >> 7;
    float acc[ROWS / 2];
#pragma unroll
    for (int j = 0; j < ROWS / 2; ++j) acc[j] = 0.f;

    for (int k = 0; k < C; ++k) {
        float wsk = ws[k * C + c];
        float wnk = wn[k * C + c];
#pragma unroll
        for (int j = 0; j < ROWS / 2; ++j) {
            int r = rhalf * (ROWS / 2) + j;
            acc[j] = fmaf(hs[r][k], wsk, acc[j]);
            acc[j] = fmaf(as[r][k], wnk, acc[j]);
        }
    }

    float bias = b[c];
#pragma unroll
    for (int j = 0; j < ROWS / 2; ++j) {
        int r = rhalf * (ROWS / 2) + j;
        int gr = r0 + r;
        if (gr < n) {
            float v = acc[j] + bias;
            h[(size_t)gr * C + c] = v > 0.f ? v : 0.f;
        }
    }
}

// ---------------- launch ----------------

extern "C" void kernel_launch(void* const* d_in, const int* in_sizes, int n_in,
                              void* d_out, int out_size, void* d_ws, size_t ws_size,
                              hipStream_t stream) {
    const float* x         = (const float*)d_in[0];
    const int*   pool_src  = (const int*)d_in[1];
    const int*   pool_dst  = (const int*)d_in[2];
    const float* pool_attr = (const float*)d_in[3];
    const int*   pp_src    = (const int*)d_in[4];
    const int*   pp_dst    = (const int*)d_in[5];
    const float* pp_attr   = (const float*)d_in[6];
    const int*   up_src    = (const int*)d_in[7];
    const int*   up_dst    = (const int*)d_in[8];
    const float* up_attr   = (const float*)d_in[9];
    const float* w[12];
    for (int i = 0; i < 12; ++i) w[i] = (const float*)d_in[10 + i];

    const int E_pool = in_sizes[1];
    const int E_pp   = in_sizes[4];
    const int E_up   = in_sizes[7];
    const int NF     = in_sizes[0] / C;  // 100000

    // workspace layout
    float* h        = (float*)d_ws;               // NC*C
    float* agg      = h + (size_t)NC * C;         // NC*C
    int*   pp_off   = (int*)(agg + (size_t)NC * C);  // NC+1
    int*   pp_cur   = pp_off + NC + 1;               // NC
    int*   pp_ssrc  = pp_cur + NC;                   // E_pp
    float* pp_sattr = (float*)(pp_ssrc + E_pp);      // E_pp
    int*   pl_off   = (int*)(pp_sattr + E_pp);       // NC+1
    int*   pl_cur   = pl_off + NC + 1;               // NC
    int*   pl_ssrc  = pl_cur + NC;                   // E_pool
    float* pl_sattr = (float*)(pl_ssrc + E_pool);    // E_pool
    int*   up_off   = (int*)(pl_sattr + E_pool);     // NF+1
    int*   up_cur   = up_off + NF + 1;               // NF
    int*   up_ssrc  = up_cur + NF;                   // E_up
    float* up_sattr = (float*)(up_ssrc + E_up);      // E_up

    const int TB = 256;

    // ---- build CSR for the three graphs ----
    // pool (dst range NC)
    hipMemsetAsync(pl_cur, 0, NC * sizeof(int), stream);
    hist_k<<<(E_pool + TB - 1) / TB, TB, 0, stream>>>(pool_dst, pl_cur, E_pool);
    scan_k<<<1, 1024, 0, stream>>>(pl_cur, pl_off, NC);
    hipMemsetAsync(pl_cur, 0, NC * sizeof(int), stream);
    fill_k<<<(E_pool + TB - 1) / TB, TB, 0, stream>>>(
        pool_src, pool_dst, pool_attr, pl_off, pl_cur, pl_ssrc, pl_sattr, E_pool);

    // pp (dst range NC)
    hipMemsetAsync(pp_cur, 0, NC * sizeof(int), stream);
    hist_k<<<(E_pp + TB - 1) / TB, TB, 0, stream>>>(pp_dst, pp_cur, E_pp);
    scan_k<<<1, 1024, 0, stream>>>(pp_cur, pp_off, NC);
    hipMemsetAsync(pp_cur, 0, NC * sizeof(int), stream);
    fill_k<<<(E_pp + TB - 1) / TB, TB, 0, stream>>>(
        pp_src, pp_dst, pp_attr, pp_off, pp_cur, pp_ssrc, pp_sattr, E_pp);

    // unpool (dst range NF)
    hipMemsetAsync(up_cur, 0, NF * sizeof(int), stream);
    hist_k<<<(E_up + TB - 1) / TB, TB, 0, stream>>>(up_dst, up_cur, E_up);
    scan_k<<<1, 1024, 0, stream>>>(up_cur, up_off, NF);
    hipMemsetAsync(up_cur, 0, NF * sizeof(int), stream);
    fill_k<<<(E_up + TB - 1) / TB, TB, 0, stream>>>(
        up_src, up_dst, up_attr, up_off, up_cur, up_ssrc, up_sattr, E_up);

    // ---- compute chain ----
    // pool: h = gather(x)
    gather_k<<<(NC + 3) / 4, 256, 0, stream>>>(x, pl_off, pl_ssrc, pl_sattr, h, NC);

    // 4 conv layers
    for (int l = 0; l < 4; ++l) {
        gather_k<<<(NC + 3) / 4, 256, 0, stream>>>(h, pp_off, pp_ssrc, pp_sattr, agg, NC);
        conv_gemm_k<<<(NC + ROWS - 1) / ROWS, 256, 0, stream>>>(
            h, agg, w[3 * l], w[3 * l + 1], w[3 * l + 2], NC);
    }

    // unpool: out = gather(h)
    gather_k<<<(NF + 3) / 4, 256, 0, stream>>>(h, up_off, up_ssrc, up_sattr, (float*)d_out, NF);
}

// Round 3
// 474.192 us; speedup vs baseline: 2.2516x; 1.2784x over previous
//
#include <hip/hip_runtime.h>
#include <hip/hip_bf16.h>

#define C 128
#define NC 25000

typedef __attribute__((ext_vector_type(8))) short bf16x8;
typedef __attribute__((ext_vector_type(4))) float f32x4;

static __device__ __forceinline__ unsigned short f2bf(float x) {
    __hip_bfloat16 h = __float2bfloat16(x);
    return __builtin_bit_cast(unsigned short, h);
}

// ---------------- CSR build ----------------

__global__ void hist_k(const int* __restrict__ dst, int* __restrict__ cnt, int nE) {
    int i = blockIdx.x * blockDim.x + threadIdx.x;
    if (i < nE) atomicAdd(&cnt[dst[i]], 1);
}

__global__ __launch_bounds__(1024) void scan_k(const int* __restrict__ cnt,
                                               int* __restrict__ off, int n) {
    __shared__ int wsum[16];
    __shared__ int s_carry;
    const int tid = threadIdx.x;
    const int lane = tid & 63;
    const int wid = tid >> 6;
    if (tid == 0) s_carry = 0;
    __syncthreads();
    for (int base = 0; base < n; base += 4096) {
        int carry = s_carry;
        int idx0 = base + tid * 4;
        int v[4];
        int s = 0;
#pragma unroll
        for (int j = 0; j < 4; ++j) {
            v[j] = (idx0 + j < n) ? cnt[idx0 + j] : 0;
            s += v[j];
        }
        int sc = s;
#pragma unroll
        for (int d = 1; d < 64; d <<= 1) {
            int t = __shfl_up(sc, d, 64);
            if (lane >= d) sc += t;
        }
        if (lane == 63) wsum[wid] = sc;
        __syncthreads();
        if (wid == 0) {
            int ws = (lane < 16) ? wsum[lane] : 0;
#pragma unroll
            for (int d = 1; d < 16; d <<= 1) {
                int t = __shfl_up(ws, d, 64);
                if (lane >= d) ws += t;
            }
            if (lane < 16) wsum[lane] = ws;
        }
        __syncthreads();
        int wave_off = (wid > 0) ? wsum[wid - 1] : 0;
        int excl = carry + wave_off + sc - s;
#pragma unroll
        for (int j = 0; j < 4; ++j) {
            if (idx0 + j < n) off[idx0 + j] = excl;
            excl += v[j];
        }
        __syncthreads();
        if (tid == 0) s_carry = carry + wsum[15];
        __syncthreads();
    }
    if (tid == 0) off[n] = s_carry;
}

__global__ void fill_k(const int* __restrict__ src, const int* __restrict__ dst,
                       const float* __restrict__ attr, const int* __restrict__ off,
                       int* __restrict__ cur, int* __restrict__ ssrc,
                       float* __restrict__ sattr, int nE) {
    int i = blockIdx.x * blockDim.x + threadIdx.x;
    if (i < nE) {
        int d = dst[i];
        int p = atomicAdd(&cur[d], 1);
        int slot = off[d] + p;
        ssrc[slot] = src[i];
        sattr[slot] = attr[i];
    }
}

// ---------------- CSR gather: out[i] = sum_e attr[e] * in[src[e]] ----------------
__global__ __launch_bounds__(256) void gather_k(
    const float* __restrict__ in, const int* __restrict__ off,
    const int* __restrict__ ssrc, const float* __restrict__ sattr,
    float* __restrict__ out, int n) {
    int node = blockIdx.x * 4 + (threadIdx.x >> 6);
    if (node >= n) return;
    int lane = threadIdx.x & 63;
    int e0 = off[node], e1 = off[node + 1];
    const float2* in2 = (const float2*)in;
    float2 acc = make_float2(0.f, 0.f);
    int e = e0;
    for (; e + 1 < e1; e += 2) {
        int s0 = ssrc[e], s1 = ssrc[e + 1];
        float a0 = sattr[e], a1 = sattr[e + 1];
        float2 v0 = in2[(size_t)s0 * 64 + lane];
        float2 v1 = in2[(size_t)s1 * 64 + lane];
        acc.x = fmaf(a0, v0.x, acc.x);
        acc.y = fmaf(a0, v0.y, acc.y);
        acc.x = fmaf(a1, v1.x, acc.x);
        acc.y = fmaf(a1, v1.y, acc.y);
    }
    if (e < e1) {
        int s0 = ssrc[e];
        float a0 = sattr[e];
        float2 v0 = in2[(size_t)s0 * 64 + lane];
        acc.x = fmaf(a0, v0.x, acc.x);
        acc.y = fmaf(a0, v0.y, acc.y);
    }
    ((float2*)out)[(size_t)node * 64 + lane] = acc;
}

// ---------------- weight prep: Wt[col][k] bf16, k<128 from ws, k>=128 from wn ----------------
__global__ void wprep_k(const float* __restrict__ ws, const float* __restrict__ wn,
                        unsigned short* __restrict__ wt) {
    int i = blockIdx.x * blockDim.x + threadIdx.x;
    if (i >= 128 * 256) return;
    int col = i >> 8, k = i & 255;
    float v = (k < 128) ? ws[k * 128 + col] : wn[(k - 128) * 128 + col];
    wt[i] = f2bf(v);
}

// ---------------- MFMA conv: hout = relu(hin@Ws + agg@Wn + b) ----------------
// One wave = 64 rows x 32 cols. Block = 4 waves = one 64-row tile, col slices.
// B-frags (weights) live in VGPRs; A streamed fp32->bf16 from global.
__global__ __launch_bounds__(256, 2) void conv_mfma_k(
    const float* __restrict__ hin, const float* __restrict__ agg,
    const unsigned short* __restrict__ wt, const float* __restrict__ bias,
    float* __restrict__ hout, int n) {
    const int wv = threadIdx.x >> 6;
    const int lane = threadIdx.x & 63;
    const int mt = blockIdx.x;
    const int col0 = wv * 32;
    const int r0 = mt * 64;
    if (r0 >= n) return;
    const int q = lane >> 4;
    const int lr = lane & 15;

    // B fragments: B[k][col], lane holds col=col0+nt*16+lr, k = kk*32+q*8+e
    bf16x8 bfr[2][8];
#pragma unroll
    for (int nt = 0; nt < 2; ++nt) {
        int col = col0 + nt * 16 + lr;
#pragma unroll
        for (int kk = 0; kk < 8; ++kk)
            bfr[nt][kk] = *(const bf16x8*)(wt + col * 256 + kk * 32 + q * 8);
    }

    f32x4 acc[4][2];
#pragma unroll
    for (int m = 0; m < 4; ++m)
#pragma unroll
        for (int nt = 0; nt < 2; ++nt) acc[m][nt] = (f32x4)(0.f);

    int rowb[4];
#pragma unroll
    for (int m = 0; m < 4; ++m) {
        int row = r0 + m * 16 + lr;
        rowb[m] = (row < n) ? row : (n - 1);
    }

#pragma unroll
    for (int kk = 0; kk < 8; ++kk) {
        const float* srcbase = (kk < 4) ? hin : agg;
        const int koff = (kk & 3) * 32 + q * 8;
#pragma unroll
        for (int m = 0; m < 4; ++m) {
            const float* p = srcbase + (size_t)rowb[m] * C + koff;
            float4 u0 = *(const float4*)p;
            float4 u1 = *(const float4*)(p + 4);
            bf16x8 a;
            a[0] = (short)f2bf(u0.x); a[1] = (short)f2bf(u0.y);
            a[2] = (short)f2bf(u0.z); a[3] = (short)f2bf(u0.w);
            a[4] = (short)f2bf(u1.x); a[5] = (short)f2bf(u1.y);
            a[6] = (short)f2bf(u1.z); a[7] = (short)f2bf(u1.w);
#pragma unroll
            for (int nt = 0; nt < 2; ++nt)
                acc[m][nt] = __builtin_amdgcn_mfma_f32_16x16x32_bf16(
                    a, bfr[nt][kk], acc[m][nt], 0, 0, 0);
        }
    }

    // epilogue: D(row,col): col = lane&15 (+nt*16+col0), row = r0+m*16+q*4+reg
#pragma unroll
    for (int nt = 0; nt < 2; ++nt) {
        int col = col0 + nt * 16 + lr;
        float bv = bias[col];
#pragma unroll
        for (int m = 0; m < 4; ++m) {
#pragma unroll
            for (int r = 0; r < 4; ++r) {
                int row = r0 + m * 16 + q * 4 + r;
                if (row < n) {
                    float v = acc[m][nt][r] + bv;
                    hout[(size_t)row * C + col] = v > 0.f ? v : 0.f;
                }
            }
        }
    }
}

// ---------------- launch ----------------

extern "C" void kernel_launch(void* const* d_in, const int* in_sizes, int n_in,
                              void* d_out, int out_size, void* d_ws, size_t ws_size,
                              hipStream_t stream) {
    const float* x         = (const float*)d_in[0];
    const int*   pool_src  = (const int*)d_in[1];
    const int*   pool_dst  = (const int*)d_in[2];
    const float* pool_attr = (const float*)d_in[3];
    const int*   pp_src    = (const int*)d_in[4];
    const int*   pp_dst    = (const int*)d_in[5];
    const float* pp_attr   = (const float*)d_in[6];
    const int*   up_src    = (const int*)d_in[7];
    const int*   up_dst    = (const int*)d_in[8];
    const float* up_attr   = (const float*)d_in[9];
    const float* w[12];
    for (int i = 0; i < 12; ++i) w[i] = (const float*)d_in[10 + i];

    const int E_pool = in_sizes[1];
    const int E_pp   = in_sizes[4];
    const int E_up   = in_sizes[7];
    const int NF     = in_sizes[0] / C;  // 100000

    // workspace layout
    float* h        = (float*)d_ws;                  // NC*C
    float* agg      = h + (size_t)NC * C;            // NC*C
    int*   pp_off   = (int*)(agg + (size_t)NC * C);  // NC+1
    int*   pp_cur   = pp_off + NC + 1;               // NC
    int*   pp_ssrc  = pp_cur + NC;                   // E_pp
    float* pp_sattr = (float*)(pp_ssrc + E_pp);      // E_pp
    int*   pl_off   = (int*)(pp_sattr + E_pp);       // NC+1
    int*   pl_cur   = pl_off + NC + 1;               // NC
    int*   pl_ssrc  = pl_cur + NC;                   // E_pool
    float* pl_sattr = (float*)(pl_ssrc + E_pool);    // E_pool
    int*   up_off   = (int*)(pl_sattr + E_pool);     // NF+1
    int*   up_cur   = up_off + NF + 1;               // NF
    int*   up_ssrc  = up_cur + NF;                   // E_up
    float* up_sattr = (float*)(up_ssrc + E_up);      // E_up
    size_t wtoff = ((size_t)(up_sattr + E_up) + 15) & ~(size_t)15;
    unsigned short* wt = (unsigned short*)wtoff;     // 4 * 128*256 bf16

    const int TB = 256;

    // ---- weight prep (4 layers) ----
    for (int l = 0; l < 4; ++l)
        wprep_k<<<(128 * 256 + TB - 1) / TB, TB, 0, stream>>>(
            w[3 * l], w[3 * l + 1], wt + (size_t)l * 128 * 256);

    // ---- build CSR for the three graphs ----
    hipMemsetAsync(pl_cur, 0, NC * sizeof(int), stream);
    hist_k<<<(E_pool + TB - 1) / TB, TB, 0, stream>>>(pool_dst, pl_cur, E_pool);
    scan_k<<<1, 1024, 0, stream>>>(pl_cur, pl_off, NC);
    hipMemsetAsync(pl_cur, 0, NC * sizeof(int), stream);
    fill_k<<<(E_pool + TB - 1) / TB, TB, 0, stream>>>(
        pool_src, pool_dst, pool_attr, pl_off, pl_cur, pl_ssrc, pl_sattr, E_pool);

    hipMemsetAsync(pp_cur, 0, NC * sizeof(int), stream);
    hist_k<<<(E_pp + TB - 1) / TB, TB, 0, stream>>>(pp_dst, pp_cur, E_pp);
    scan_k<<<1, 1024, 0, stream>>>(pp_cur, pp_off, NC);
    hipMemsetAsync(pp_cur, 0, NC * sizeof(int), stream);
    fill_k<<<(E_pp + TB - 1) / TB, TB, 0, stream>>>(
        pp_src, pp_dst, pp_attr, pp_off, pp_cur, pp_ssrc, pp_sattr, E_pp);

    hipMemsetAsync(up_cur, 0, NF * sizeof(int), stream);
    hist_k<<<(E_up + TB - 1) / TB, TB, 0, stream>>>(up_dst, up_cur, E_up);
    scan_k<<<1, 1024, 0, stream>>>(up_cur, up_off, NF);
    hipMemsetAsync(up_cur, 0, NF * sizeof(int), stream);
    fill_k<<<(E_up + TB - 1) / TB, TB, 0, stream>>>(
        up_src, up_dst, up_attr, up_off, up_cur, up_ssrc, up_sattr, E_up);

    // ---- compute chain ----
    gather_k<<<(NC + 3) / 4, 256, 0, stream>>>(x, pl_off, pl_ssrc, pl_sattr, h, NC);

    // ping-pong h through d_out (scratch until final unpool overwrites it)
    float* hcur = h;
    float* halt = (float*)d_out;
    const int mtiles = (NC + 63) / 64;
    for (int l = 0; l < 4; ++l) {
        gather_k<<<(NC + 3) / 4, 256, 0, stream>>>(hcur, pp_off, pp_ssrc, pp_sattr, agg, NC);
        conv_mfma_k<<<mtiles, 256, 0, stream>>>(
            hcur, agg, wt + (size_t)l * 128 * 256, w[3 * l + 2], halt, NC);
        float* t = hcur; hcur = halt; halt = t;
    }

    // unpool: out = gather(h) ; hcur == h (ws) after 4 swaps, halt == d_out
    gather_k<<<(NF + 3) / 4, 256, 0, stream>>>(hcur, up_off, up_ssrc, up_sattr, (float*)d_out, NF);
}

// Round 4
// 410.704 us; speedup vs baseline: 2.5997x; 1.1546x over previous
//
#include <hip/hip_runtime.h>
#include <hip/hip_bf16.h>

#define C 128
#define NC 25000
#define SCHUNK 4096

typedef __attribute__((ext_vector_type(8))) short bf16x8;
typedef __attribute__((ext_vector_type(4))) float f32x4;

static __device__ __forceinline__ unsigned short f2bf(float x) {
    __hip_bfloat16 h = __float2bfloat16(x);
    return __builtin_bit_cast(unsigned short, h);
}

// ---------------- CSR build ----------------

__global__ void hist_k(const int* __restrict__ dst, int* __restrict__ cnt, int nE) {
    int i = blockIdx.x * blockDim.x + threadIdx.x;
    if (i < nE) atomicAdd(&cnt[dst[i]], 1);
}

// Hierarchical scan, step 1: per-chunk sums.
__global__ __launch_bounds__(256) void reduce_k(const int* __restrict__ cnt,
                                                int* __restrict__ bsum, int n) {
    __shared__ int wpart[4];
    int base = blockIdx.x * SCHUNK;
    int tid = threadIdx.x;
    int end = base + SCHUNK; if (end > n) end = n;
    int s = 0;
    for (int i = base + tid; i < end; i += 256) s += cnt[i];
#pragma unroll
    for (int d = 32; d > 0; d >>= 1) s += __shfl_down(s, d, 64);
    if ((tid & 63) == 0) wpart[tid >> 6] = s;
    __syncthreads();
    if (tid == 0) bsum[blockIdx.x] = wpart[0] + wpart[1] + wpart[2] + wpart[3];
}

// step 2: exclusive scan of <=64 chunk sums (in place); writes off[n] = total.
__global__ void scan_bsum_k(int* __restrict__ bsum, int* __restrict__ off,
                            int nb, int n) {
    int lane = threadIdx.x;
    int orig = (lane < nb) ? bsum[lane] : 0;
    int incl = orig;
#pragma unroll
    for (int d = 1; d < 64; d <<= 1) {
        int t = __shfl_up(incl, d, 64);
        if (lane >= d) incl += t;
    }
    if (lane < nb) bsum[lane] = incl - orig;
    if (lane == 63) off[n] = incl;
}

// step 3: per-chunk local exclusive scan + chunk prefix.
__global__ __launch_bounds__(1024) void scan_blk_k(const int* __restrict__ cnt,
                                                   const int* __restrict__ bexcl,
                                                   int* __restrict__ off, int n) {
    __shared__ int wsum[16];
    const int tid = threadIdx.x, lane = tid & 63, wid = tid >> 6;
    int idx0 = blockIdx.x * SCHUNK + tid * 4;
    int v[4]; int s = 0;
#pragma unroll
    for (int j = 0; j < 4; ++j) { v[j] = (idx0 + j < n) ? cnt[idx0 + j] : 0; s += v[j]; }
    int sc = s;
#pragma unroll
    for (int d = 1; d < 64; d <<= 1) {
        int t = __shfl_up(sc, d, 64);
        if (lane >= d) sc += t;
    }
    if (lane == 63) wsum[wid] = sc;
    __syncthreads();
    if (wid == 0) {
        int ws = (lane < 16) ? wsum[lane] : 0;
#pragma unroll
        for (int d = 1; d < 16; d <<= 1) {
            int t = __shfl_up(ws, d, 64);
            if (lane >= d) ws += t;
        }
        if (lane < 16) wsum[lane] = ws;
    }
    __syncthreads();
    int wave_off = (wid > 0) ? wsum[wid - 1] : 0;
    int excl = bexcl[blockIdx.x] + wave_off + sc - s;
#pragma unroll
    for (int j = 0; j < 4; ++j) {
        if (idx0 + j < n) off[idx0 + j] = excl;
        excl += v[j];
    }
}

__global__ void fill_k(const int* __restrict__ src, const int* __restrict__ dst,
                       const float* __restrict__ attr, const int* __restrict__ off,
                       int* __restrict__ cur, int* __restrict__ ssrc,
                       float* __restrict__ sattr, int nE) {
    int i = blockIdx.x * blockDim.x + threadIdx.x;
    if (i < nE) {
        int d = dst[i];
        int p = atomicAdd(&cur[d], 1);
        int slot = off[d] + p;
        ssrc[slot] = src[i];
        sattr[slot] = attr[i];
    }
}

// ---------------- CSR gather: out[i] = sum_e attr[e] * in[src[e]] ----------------
__global__ __launch_bounds__(256) void gather_k(
    const float* __restrict__ in, const int* __restrict__ off,
    const int* __restrict__ ssrc, const float* __restrict__ sattr,
    float* __restrict__ out, int n) {
    int node = blockIdx.x * 4 + (threadIdx.x >> 6);
    if (node >= n) return;
    int lane = threadIdx.x & 63;
    int e0 = off[node], e1 = off[node + 1];
    const float2* in2 = (const float2*)in;
    float2 acc = make_float2(0.f, 0.f);
    int e = e0;
    for (; e + 1 < e1; e += 2) {
        int s0 = ssrc[e], s1 = ssrc[e + 1];
        float a0 = sattr[e], a1 = sattr[e + 1];
        float2 v0 = in2[(size_t)s0 * 64 + lane];
        float2 v1 = in2[(size_t)s1 * 64 + lane];
        acc.x = fmaf(a0, v0.x, acc.x);
        acc.y = fmaf(a0, v0.y, acc.y);
        acc.x = fmaf(a1, v1.x, acc.x);
        acc.y = fmaf(a1, v1.y, acc.y);
    }
    if (e < e1) {
        int s0 = ssrc[e];
        float a0 = sattr[e];
        float2 v0 = in2[(size_t)s0 * 64 + lane];
        acc.x = fmaf(a0, v0.x, acc.x);
        acc.y = fmaf(a0, v0.y, acc.y);
    }
    ((float2*)out)[(size_t)node * 64 + lane] = acc;
}

// ---------------- weight prep: Wt[col][k] bf16 ----------------
__global__ void wprep_k(const float* __restrict__ ws, const float* __restrict__ wn,
                        unsigned short* __restrict__ wt) {
    int i = blockIdx.x * blockDim.x + threadIdx.x;
    if (i >= 128 * 256) return;
    int col = i >> 8, k = i & 255;
    float v = (k < 128) ? ws[k * 128 + col] : wn[(k - 128) * 128 + col];
    wt[i] = f2bf(v);
}

// ---------------- MFMA conv: hout = relu(hin@Ws + agg@Wn + b) ----------------
__global__ __launch_bounds__(256, 2) void conv_mfma_k(
    const float* __restrict__ hin, const float* __restrict__ agg,
    const unsigned short* __restrict__ wt, const float* __restrict__ bias,
    float* __restrict__ hout, int n) {
    const int wv = threadIdx.x >> 6;
    const int lane = threadIdx.x & 63;
    const int mt = blockIdx.x;
    const int col0 = wv * 32;
    const int r0 = mt * 64;
    if (r0 >= n) return;
    const int q = lane >> 4;
    const int lr = lane & 15;

    bf16x8 bfr[2][8];
#pragma unroll
    for (int nt = 0; nt < 2; ++nt) {
        int col = col0 + nt * 16 + lr;
#pragma unroll
        for (int kk = 0; kk < 8; ++kk)
            bfr[nt][kk] = *(const bf16x8*)(wt + col * 256 + kk * 32 + q * 8);
    }

    f32x4 acc[4][2];
#pragma unroll
    for (int m = 0; m < 4; ++m)
#pragma unroll
        for (int nt = 0; nt < 2; ++nt) acc[m][nt] = (f32x4)(0.f);

    int rowb[4];
#pragma unroll
    for (int m = 0; m < 4; ++m) {
        int row = r0 + m * 16 + lr;
        rowb[m] = (row < n) ? row : (n - 1);
    }

#pragma unroll
    for (int kk = 0; kk < 8; ++kk) {
        const float* srcbase = (kk < 4) ? hin : agg;
        const int koff = (kk & 3) * 32 + q * 8;
#pragma unroll
        for (int m = 0; m < 4; ++m) {
            const float* p = srcbase + (size_t)rowb[m] * C + koff;
            float4 u0 = *(const float4*)p;
            float4 u1 = *(const float4*)(p + 4);
            bf16x8 a;
            a[0] = (short)f2bf(u0.x); a[1] = (short)f2bf(u0.y);
            a[2] = (short)f2bf(u0.z); a[3] = (short)f2bf(u0.w);
            a[4] = (short)f2bf(u1.x); a[5] = (short)f2bf(u1.y);
            a[6] = (short)f2bf(u1.z); a[7] = (short)f2bf(u1.w);
#pragma unroll
            for (int nt = 0; nt < 2; ++nt)
                acc[m][nt] = __builtin_amdgcn_mfma_f32_16x16x32_bf16(
                    a, bfr[nt][kk], acc[m][nt], 0, 0, 0);
        }
    }

#pragma unroll
    for (int nt = 0; nt < 2; ++nt) {
        int col = col0 + nt * 16 + lr;
        float bv = bias[col];
#pragma unroll
        for (int m = 0; m < 4; ++m) {
#pragma unroll
            for (int r = 0; r < 4; ++r) {
                int row = r0 + m * 16 + q * 4 + r;
                if (row < n) {
                    float v = acc[m][nt][r] + bv;
                    hout[(size_t)row * C + col] = v > 0.f ? v : 0.f;
                }
            }
        }
    }
}

// ---------------- launch ----------------

extern "C" void kernel_launch(void* const* d_in, const int* in_sizes, int n_in,
                              void* d_out, int out_size, void* d_ws, size_t ws_size,
                              hipStream_t stream) {
    const float* x         = (const float*)d_in[0];
    const int*   pool_src  = (const int*)d_in[1];
    const int*   pool_dst  = (const int*)d_in[2];
    const float* pool_attr = (const float*)d_in[3];
    const int*   pp_src    = (const int*)d_in[4];
    const int*   pp_dst    = (const int*)d_in[5];
    const float* pp_attr   = (const float*)d_in[6];
    const int*   up_src    = (const int*)d_in[7];
    const int*   up_dst    = (const int*)d_in[8];
    const float* up_attr   = (const float*)d_in[9];
    const float* w[12];
    for (int i = 0; i < 12; ++i) w[i] = (const float*)d_in[10 + i];

    const int E_pool = in_sizes[1];
    const int E_pp   = in_sizes[4];
    const int E_up   = in_sizes[7];
    const int NF     = in_sizes[0] / C;  // 100000

    // workspace layout
    float* h        = (float*)d_ws;                  // NC*C
    float* agg      = h + (size_t)NC * C;            // NC*C
    int*   pp_off   = (int*)(agg + (size_t)NC * C);  // NC+1
    int*   pp_cur   = pp_off + NC + 1;               // NC
    int*   pp_ssrc  = pp_cur + NC;                   // E_pp
    float* pp_sattr = (float*)(pp_ssrc + E_pp);      // E_pp
    int*   pl_off   = (int*)(pp_sattr + E_pp);       // NC+1
    int*   pl_cur   = pl_off + NC + 1;               // NC
    int*   pl_ssrc  = pl_cur + NC;                   // E_pool
    float* pl_sattr = (float*)(pl_ssrc + E_pool);    // E_pool
    int*   up_off   = (int*)(pl_sattr + E_pool);     // NF+1
    int*   up_cur   = up_off + NF + 1;               // NF
    int*   up_ssrc  = up_cur + NF;                   // E_up
    float* up_sattr = (float*)(up_ssrc + E_up);      // E_up
    size_t wtoff = ((size_t)(up_sattr + E_up) + 15) & ~(size_t)15;
    unsigned short* wt = (unsigned short*)wtoff;     // 4 * 128*256 bf16
    int* bsum = (int*)(wt + 4 * 128 * 256);          // 64 ints (shared by all scans)

    const int TB = 256;

    // ---- weight prep (4 layers) ----
    for (int l = 0; l < 4; ++l)
        wprep_k<<<(128 * 256 + TB - 1) / TB, TB, 0, stream>>>(
            w[3 * l], w[3 * l + 1], wt + (size_t)l * 128 * 256);

    // hierarchical scan helper (stream-serialized, so bsum is safely reused)
    auto run_scan = [&](const int* cnt, int* off, int n) {
        int nb = (n + SCHUNK - 1) / SCHUNK;
        reduce_k<<<nb, 256, 0, stream>>>(cnt, bsum, n);
        scan_bsum_k<<<1, 64, 0, stream>>>(bsum, off, nb, n);
        scan_blk_k<<<nb, 1024, 0, stream>>>(cnt, bsum, off, n);
    };

    // ---- build CSR for the three graphs ----
    hipMemsetAsync(pl_cur, 0, NC * sizeof(int), stream);
    hist_k<<<(E_pool + TB - 1) / TB, TB, 0, stream>>>(pool_dst, pl_cur, E_pool);
    run_scan(pl_cur, pl_off, NC);
    hipMemsetAsync(pl_cur, 0, NC * sizeof(int), stream);
    fill_k<<<(E_pool + TB - 1) / TB, TB, 0, stream>>>(
        pool_src, pool_dst, pool_attr, pl_off, pl_cur, pl_ssrc, pl_sattr, E_pool);

    hipMemsetAsync(pp_cur, 0, NC * sizeof(int), stream);
    hist_k<<<(E_pp + TB - 1) / TB, TB, 0, stream>>>(pp_dst, pp_cur, E_pp);
    run_scan(pp_cur, pp_off, NC);
    hipMemsetAsync(pp_cur, 0, NC * sizeof(int), stream);
    fill_k<<<(E_pp + TB - 1) / TB, TB, 0, stream>>>(
        pp_src, pp_dst, pp_attr, pp_off, pp_cur, pp_ssrc, pp_sattr, E_pp);

    hipMemsetAsync(up_cur, 0, NF * sizeof(int), stream);
    hist_k<<<(E_up + TB - 1) / TB, TB, 0, stream>>>(up_dst, up_cur, E_up);
    run_scan(up_cur, up_off, NF);
    hipMemsetAsync(up_cur, 0, NF * sizeof(int), stream);
    fill_k<<<(E_up + TB - 1) / TB, TB, 0, stream>>>(
        up_src, up_dst, up_attr, up_off, up_cur, up_ssrc, up_sattr, E_up);

    // ---- compute chain ----
    gather_k<<<(NC + 3) / 4, 256, 0, stream>>>(x, pl_off, pl_ssrc, pl_sattr, h, NC);

    // ping-pong h through d_out (scratch until final unpool overwrites it)
    float* hcur = h;
    float* halt = (float*)d_out;
    const int mtiles = (NC + 63) / 64;
    for (int l = 0; l < 4; ++l) {
        gather_k<<<(NC + 3) / 4, 256, 0, stream>>>(hcur, pp_off, pp_ssrc, pp_sattr, agg, NC);
        conv_mfma_k<<<mtiles, 256, 0, stream>>>(
            hcur, agg, wt + (size_t)l * 128 * 256, w[3 * l + 2], halt, NC);
        float* t = hcur; hcur = halt; halt = t;
    }

    // unpool: out = gather(h); hcur == h (ws) after 4 swaps
    gather_k<<<(NF + 3) / 4, 256, 0, stream>>>(hcur, up_off, up_ssrc, up_sattr, (float*)d_out, NF);
}

// Round 5
// 334.089 us; speedup vs baseline: 3.1958x; 1.2293x over previous
//
#include <hip/hip_runtime.h>
#include <hip/hip_bf16.h>

#define C 128
#define NC 25000
#define SCHUNK 4096

typedef __attribute__((ext_vector_type(8))) short bf16x8;
typedef __attribute__((ext_vector_type(4))) float f32x4;

static __device__ __forceinline__ unsigned short f2bf(float x) {
    __hip_bfloat16 h = __float2bfloat16(x);
    return __builtin_bit_cast(unsigned short, h);
}
static __device__ __forceinline__ float bflo(unsigned int v) {
    return __builtin_bit_cast(float, v << 16);
}
static __device__ __forceinline__ float bfhi(unsigned int v) {
    return __builtin_bit_cast(float, v & 0xffff0000u);
}

// ---------------- CSR build ----------------

__global__ void hist_k(const int* __restrict__ dst, int* __restrict__ cnt, int nE) {
    int i = blockIdx.x * blockDim.x + threadIdx.x;
    if (i < nE) atomicAdd(&cnt[dst[i]], 1);
}

__global__ __launch_bounds__(256) void reduce_k(const int* __restrict__ cnt,
                                                int* __restrict__ bsum, int n) {
    __shared__ int wpart[4];
    int base = blockIdx.x * SCHUNK;
    int tid = threadIdx.x;
    int end = base + SCHUNK; if (end > n) end = n;
    int s = 0;
    for (int i = base + tid; i < end; i += 256) s += cnt[i];
#pragma unroll
    for (int d = 32; d > 0; d >>= 1) s += __shfl_down(s, d, 64);
    if ((tid & 63) == 0) wpart[tid >> 6] = s;
    __syncthreads();
    if (tid == 0) bsum[blockIdx.x] = wpart[0] + wpart[1] + wpart[2] + wpart[3];
}

__global__ void scan_bsum_k(int* __restrict__ bsum, int* __restrict__ off,
                            int nb, int n) {
    int lane = threadIdx.x;
    int orig = (lane < nb) ? bsum[lane] : 0;
    int incl = orig;
#pragma unroll
    for (int d = 1; d < 64; d <<= 1) {
        int t = __shfl_up(incl, d, 64);
        if (lane >= d) incl += t;
    }
    if (lane < nb) bsum[lane] = incl - orig;
    if (lane == 63) off[n] = incl;
}

__global__ __launch_bounds__(1024) void scan_blk_k(const int* __restrict__ cnt,
                                                   const int* __restrict__ bexcl,
                                                   int* __restrict__ off, int n) {
    __shared__ int wsum[16];
    const int tid = threadIdx.x, lane = tid & 63, wid = tid >> 6;
    int idx0 = blockIdx.x * SCHUNK + tid * 4;
    int v[4]; int s = 0;
#pragma unroll
    for (int j = 0; j < 4; ++j) { v[j] = (idx0 + j < n) ? cnt[idx0 + j] : 0; s += v[j]; }
    int sc = s;
#pragma unroll
    for (int d = 1; d < 64; d <<= 1) {
        int t = __shfl_up(sc, d, 64);
        if (lane >= d) sc += t;
    }
    if (lane == 63) wsum[wid] = sc;
    __syncthreads();
    if (wid == 0) {
        int ws = (lane < 16) ? wsum[lane] : 0;
#pragma unroll
        for (int d = 1; d < 16; d <<= 1) {
            int t = __shfl_up(ws, d, 64);
            if (lane >= d) ws += t;
        }
        if (lane < 16) wsum[lane] = ws;
    }
    __syncthreads();
    int wave_off = (wid > 0) ? wsum[wid - 1] : 0;
    int excl = bexcl[blockIdx.x] + wave_off + sc - s;
#pragma unroll
    for (int j = 0; j < 4; ++j) {
        if (idx0 + j < n) off[idx0 + j] = excl;
        excl += v[j];
    }
}

// fill packed edges: ep[slot] = {src, bitcast(attr)}
__global__ void fill_k(const int* __restrict__ src, const int* __restrict__ dst,
                       const float* __restrict__ attr, const int* __restrict__ off,
                       int* __restrict__ cur, int2* __restrict__ ep, int nE) {
    int i = blockIdx.x * blockDim.x + threadIdx.x;
    if (i < nE) {
        int d = dst[i];
        int p = atomicAdd(&cur[d], 1);
        ep[off[d] + p] = make_int2(src[i], __float_as_int(attr[i]));
    }
}

// ---------------- CSR gather: out[i] = sum_e attr[e] * in[src[e]] ----------------
// One wave per node, lane = 2 channels. IN/OUT dtype via flags.
template<bool IN_BF16, bool OUT_BF16>
__global__ __launch_bounds__(256) void gather_k(
    const void* __restrict__ in_, const int* __restrict__ off,
    const int2* __restrict__ ep, void* __restrict__ out_, int n) {
    int node = blockIdx.x * 4 + (threadIdx.x >> 6);
    if (node >= n) return;
    int lane = threadIdx.x & 63;
    int e0 = off[node], e1 = off[node + 1];
    float ax = 0.f, ay = 0.f;
    const unsigned int* inb = (const unsigned int*)in_;  // bf16 row: 64 uints
    const float2* inf = (const float2*)in_;

    int e = e0;
    for (; e + 3 < e1; e += 4) {
        int2 p0 = ep[e], p1 = ep[e + 1], p2 = ep[e + 2], p3 = ep[e + 3];
        if (IN_BF16) {
            unsigned int v0 = inb[(size_t)p0.x * 64 + lane];
            unsigned int v1 = inb[(size_t)p1.x * 64 + lane];
            unsigned int v2 = inb[(size_t)p2.x * 64 + lane];
            unsigned int v3 = inb[(size_t)p3.x * 64 + lane];
            float a0 = __int_as_float(p0.y), a1 = __int_as_float(p1.y);
            float a2 = __int_as_float(p2.y), a3 = __int_as_float(p3.y);
            ax = fmaf(a0, bflo(v0), ax); ay = fmaf(a0, bfhi(v0), ay);
            ax = fmaf(a1, bflo(v1), ax); ay = fmaf(a1, bfhi(v1), ay);
            ax = fmaf(a2, bflo(v2), ax); ay = fmaf(a2, bfhi(v2), ay);
            ax = fmaf(a3, bflo(v3), ax); ay = fmaf(a3, bfhi(v3), ay);
        } else {
            float2 v0 = inf[(size_t)p0.x * 64 + lane];
            float2 v1 = inf[(size_t)p1.x * 64 + lane];
            float2 v2 = inf[(size_t)p2.x * 64 + lane];
            float2 v3 = inf[(size_t)p3.x * 64 + lane];
            float a0 = __int_as_float(p0.y), a1 = __int_as_float(p1.y);
            float a2 = __int_as_float(p2.y), a3 = __int_as_float(p3.y);
            ax = fmaf(a0, v0.x, ax); ay = fmaf(a0, v0.y, ay);
            ax = fmaf(a1, v1.x, ax); ay = fmaf(a1, v1.y, ay);
            ax = fmaf(a2, v2.x, ax); ay = fmaf(a2, v2.y, ay);
            ax = fmaf(a3, v3.x, ax); ay = fmaf(a3, v3.y, ay);
        }
    }
    for (; e < e1; ++e) {
        int2 p0 = ep[e];
        float a0 = __int_as_float(p0.y);
        if (IN_BF16) {
            unsigned int v0 = inb[(size_t)p0.x * 64 + lane];
            ax = fmaf(a0, bflo(v0), ax); ay = fmaf(a0, bfhi(v0), ay);
        } else {
            float2 v0 = inf[(size_t)p0.x * 64 + lane];
            ax = fmaf(a0, v0.x, ax); ay = fmaf(a0, v0.y, ay);
        }
    }

    if (OUT_BF16) {
        unsigned int lo = f2bf(ax), hi = f2bf(ay);
        ((unsigned int*)out_)[(size_t)node * 64 + lane] = lo | (hi << 16);
    } else {
        ((float2*)out_)[(size_t)node * 64 + lane] = make_float2(ax, ay);
    }
}

// ---------------- weight prep: Wt[col][k] bf16 ----------------
__global__ void wprep_k(const float* __restrict__ ws, const float* __restrict__ wn,
                        unsigned short* __restrict__ wt) {
    int i = blockIdx.x * blockDim.x + threadIdx.x;
    if (i >= 128 * 256) return;
    int col = i >> 8, k = i & 255;
    float v = (k < 128) ? ws[k * 128 + col] : wn[(k - 128) * 128 + col];
    wt[i] = f2bf(v);
}

// ---------------- MFMA conv: hout = relu(hin@Ws + agg@Wn + b), all bf16 ----------------
// One wave = 64 rows x 32 cols; block = 4 waves (full 128 cols of a 64-row tile).
__global__ __launch_bounds__(256, 2) void conv_mfma_k(
    const unsigned short* __restrict__ hin, const unsigned short* __restrict__ agg,
    const unsigned short* __restrict__ wt, const float* __restrict__ bias,
    unsigned short* __restrict__ hout, int n) {
    const int wv = threadIdx.x >> 6;
    const int lane = threadIdx.x & 63;
    const int col0 = wv * 32;
    const int r0 = blockIdx.x * 64;
    if (r0 >= n) return;
    const int q = lane >> 4;
    const int lr = lane & 15;

    // B fragments: lane holds col=col0+nt*16+lr, k = kk*32+q*8+e
    bf16x8 bfr[2][8];
#pragma unroll
    for (int nt = 0; nt < 2; ++nt) {
        int col = col0 + nt * 16 + lr;
#pragma unroll
        for (int kk = 0; kk < 8; ++kk)
            bfr[nt][kk] = *(const bf16x8*)(wt + col * 256 + kk * 32 + q * 8);
    }

    f32x4 acc[4][2];
#pragma unroll
    for (int m = 0; m < 4; ++m)
#pragma unroll
        for (int nt = 0; nt < 2; ++nt) acc[m][nt] = (f32x4)(0.f);

    int rowb[4];
#pragma unroll
    for (int m = 0; m < 4; ++m) {
        int row = r0 + m * 16 + lr;
        rowb[m] = (row < n) ? row : (n - 1);
    }

#pragma unroll
    for (int kk = 0; kk < 8; ++kk) {
        const unsigned short* srcbase = (kk < 4) ? hin : agg;
        const int koff = (kk & 3) * 32 + q * 8;
#pragma unroll
        for (int m = 0; m < 4; ++m) {
            bf16x8 a = *(const bf16x8*)(srcbase + (size_t)rowb[m] * C + koff);
#pragma unroll
            for (int nt = 0; nt < 2; ++nt)
                acc[m][nt] = __builtin_amdgcn_mfma_f32_16x16x32_bf16(
                    a, bfr[nt][kk], acc[m][nt], 0, 0, 0);
        }
    }

    // epilogue: D(row,col): col = col0+nt*16+(lane&15), row = r0+m*16+q*4+r
#pragma unroll
    for (int nt = 0; nt < 2; ++nt) {
        int col = col0 + nt * 16 + lr;
        float bv = bias[col];
#pragma unroll
        for (int m = 0; m < 4; ++m) {
#pragma unroll
            for (int r = 0; r < 4; ++r) {
                int row = r0 + m * 16 + q * 4 + r;
                if (row < n) {
                    float v = acc[m][nt][r] + bv;
                    hout[(size_t)row * C + col] = f2bf(v > 0.f ? v : 0.f);
                }
            }
        }
    }
}

// ---------------- launch ----------------

extern "C" void kernel_launch(void* const* d_in, const int* in_sizes, int n_in,
                              void* d_out, int out_size, void* d_ws, size_t ws_size,
                              hipStream_t stream) {
    const float* x         = (const float*)d_in[0];
    const int*   pool_src  = (const int*)d_in[1];
    const int*   pool_dst  = (const int*)d_in[2];
    const float* pool_attr = (const float*)d_in[3];
    const int*   pp_src    = (const int*)d_in[4];
    const int*   pp_dst    = (const int*)d_in[5];
    const float* pp_attr   = (const float*)d_in[6];
    const int*   up_src    = (const int*)d_in[7];
    const int*   up_dst    = (const int*)d_in[8];
    const float* up_attr   = (const float*)d_in[9];
    const float* w[12];
    for (int i = 0; i < 12; ++i) w[i] = (const float*)d_in[10 + i];

    const int E_pool = in_sizes[1];
    const int E_pp   = in_sizes[4];
    const int E_up   = in_sizes[7];
    const int NF     = in_sizes[0] / C;  // 100000

    // workspace layout (bf16 h buffers)
    unsigned short* h   = (unsigned short*)d_ws;         // NC*C bf16
    unsigned short* h2  = h + (size_t)NC * C;            // NC*C bf16
    unsigned short* agg = h2 + (size_t)NC * C;           // NC*C bf16
    int*  pp_off  = (int*)(agg + (size_t)NC * C);        // NC+1
    int*  pp_cur  = pp_off + NC + 1;                     // NC
    int2* pp_ep   = (int2*)(pp_cur + NC);                // E_pp
    int*  pl_off  = (int*)(pp_ep + E_pp);                // NC+1
    int*  pl_cur  = pl_off + NC + 1;                     // NC
    int2* pl_ep   = (int2*)(pl_cur + NC);                // E_pool
    int*  up_off  = (int*)(pl_ep + E_pool);              // NF+1
    int*  up_cur  = up_off + NF + 1;                     // NF
    int2* up_ep   = (int2*)(up_cur + NF);                // E_up
    unsigned short* wt = (unsigned short*)(up_ep + E_up);  // 4*128*256 bf16
    int* bsum = (int*)(wt + 4 * 128 * 256);              // 64 ints

    const int TB = 256;

    // ---- weight prep ----
    for (int l = 0; l < 4; ++l)
        wprep_k<<<(128 * 256 + TB - 1) / TB, TB, 0, stream>>>(
            w[3 * l], w[3 * l + 1], wt + (size_t)l * 128 * 256);

    auto run_scan = [&](const int* cnt, int* off, int n) {
        int nb = (n + SCHUNK - 1) / SCHUNK;
        reduce_k<<<nb, 256, 0, stream>>>(cnt, bsum, n);
        scan_bsum_k<<<1, 64, 0, stream>>>(bsum, off, nb, n);
        scan_blk_k<<<nb, 1024, 0, stream>>>(cnt, bsum, off, n);
    };

    // ---- build CSR for the three graphs ----
    hipMemsetAsync(pl_cur, 0, NC * sizeof(int), stream);
    hist_k<<<(E_pool + TB - 1) / TB, TB, 0, stream>>>(pool_dst, pl_cur, E_pool);
    run_scan(pl_cur, pl_off, NC);
    hipMemsetAsync(pl_cur, 0, NC * sizeof(int), stream);
    fill_k<<<(E_pool + TB - 1) / TB, TB, 0, stream>>>(
        pool_src, pool_dst, pool_attr, pl_off, pl_cur, pl_ep, E_pool);

    hipMemsetAsync(pp_cur, 0, NC * sizeof(int), stream);
    hist_k<<<(E_pp + TB - 1) / TB, TB, 0, stream>>>(pp_dst, pp_cur, E_pp);
    run_scan(pp_cur, pp_off, NC);
    hipMemsetAsync(pp_cur, 0, NC * sizeof(int), stream);
    fill_k<<<(E_pp + TB - 1) / TB, TB, 0, stream>>>(
        pp_src, pp_dst, pp_attr, pp_off, pp_cur, pp_ep, E_pp);

    hipMemsetAsync(up_cur, 0, NF * sizeof(int), stream);
    hist_k<<<(E_up + TB - 1) / TB, TB, 0, stream>>>(up_dst, up_cur, E_up);
    run_scan(up_cur, up_off, NF);
    hipMemsetAsync(up_cur, 0, NF * sizeof(int), stream);
    fill_k<<<(E_up + TB - 1) / TB, TB, 0, stream>>>(
        up_src, up_dst, up_attr, up_off, up_cur, up_ep, E_up);

    // ---- compute chain ----
    // pool: h = gather(x fp32) -> bf16
    gather_k<false, true><<<(NC + 3) / 4, 256, 0, stream>>>(x, pl_off, pl_ep, h, NC);

    unsigned short* hcur = h;
    unsigned short* halt = h2;
    const int mtiles = (NC + 63) / 64;
    for (int l = 0; l < 4; ++l) {
        gather_k<true, true><<<(NC + 3) / 4, 256, 0, stream>>>(hcur, pp_off, pp_ep, agg, NC);
        conv_mfma_k<<<mtiles, 256, 0, stream>>>(
            hcur, agg, wt + (size_t)l * 128 * 256, w[3 * l + 2], halt, NC);
        unsigned short* t = hcur; hcur = halt; halt = t;
    }

    // unpool: out(fp32) = gather(h bf16)
    gather_k<true, false><<<(NF + 3) / 4, 256, 0, stream>>>(hcur, up_off, up_ep, (float*)d_out, NF);
}

// Round 6
// 272.957 us; speedup vs baseline: 3.9116x; 1.2240x over previous
//
#include <hip/hip_runtime.h>
#include <hip/hip_bf16.h>

#define C 128
#define NC 25000
#define SCHUNK 4096

typedef __attribute__((ext_vector_type(8))) short bf16x8;
typedef __attribute__((ext_vector_type(4))) float f32x4;

static __device__ __forceinline__ unsigned short f2bf(float x) {
    __hip_bfloat16 h = __float2bfloat16(x);
    return __builtin_bit_cast(unsigned short, h);
}
static __device__ __forceinline__ float bflo(unsigned int v) {
    return __builtin_bit_cast(float, v << 16);
}
static __device__ __forceinline__ float bfhi(unsigned int v) {
    return __builtin_bit_cast(float, v & 0xffff0000u);
}

// ---------------- fused CSR build over 3 concatenated graphs ----------------
// cnt/cur layout: [pool: 0..NC) [pp: NC..2NC) [up: 2NC..2NC+NF)
// ep_all slots come from the GLOBAL exclusive scan of the concatenated counts,
// so per-graph off arrays are just slices of off_all and all graphs share ep_all.

__global__ __launch_bounds__(256) void hist3_k(
    const int* __restrict__ pl_dst, const int* __restrict__ pp_dst,
    const int* __restrict__ up_dst, int* __restrict__ cnt,
    int Epl, int Epp, int Eup) {
    int i = blockIdx.x * blockDim.x + threadIdx.x;
    if (i < Epl) {
        atomicAdd(&cnt[pl_dst[i]], 1);
    } else if (i < Epl + Epp) {
        atomicAdd(&cnt[NC + pp_dst[i - Epl]], 1);
    } else if (i < Epl + Epp + Eup) {
        atomicAdd(&cnt[2 * NC + up_dst[i - Epl - Epp]], 1);
    }
}

__global__ __launch_bounds__(256) void fill3_k(
    const int* __restrict__ pl_src, const float* __restrict__ pl_attr,
    const int* __restrict__ pp_src, const float* __restrict__ pp_attr,
    const int* __restrict__ up_src, const float* __restrict__ up_attr,
    const int* __restrict__ pl_dst, const int* __restrict__ pp_dst,
    const int* __restrict__ up_dst,
    const int* __restrict__ off, int* __restrict__ cur,
    int2* __restrict__ ep, int Epl, int Epp, int Eup) {
    int i = blockIdx.x * blockDim.x + threadIdx.x;
    int cidx, s; float a;
    if (i < Epl) {
        cidx = pl_dst[i]; s = pl_src[i]; a = pl_attr[i];
    } else if (i < Epl + Epp) {
        int j = i - Epl;
        cidx = NC + pp_dst[j]; s = pp_src[j]; a = pp_attr[j];
    } else if (i < Epl + Epp + Eup) {
        int j = i - Epl - Epp;
        cidx = 2 * NC + up_dst[j]; s = up_src[j]; a = up_attr[j];
    } else return;
    int p = atomicAdd(&cur[cidx], 1);
    ep[off[cidx] + p] = make_int2(s, __float_as_int(a));
}

// ---------------- hierarchical scan (3 dispatches, parallel chunks) ----------------

__global__ __launch_bounds__(256) void reduce_k(const int* __restrict__ cnt,
                                                int* __restrict__ bsum, int n) {
    __shared__ int wpart[4];
    int base = blockIdx.x * SCHUNK;
    int tid = threadIdx.x;
    int end = base + SCHUNK; if (end > n) end = n;
    int s = 0;
    for (int i = base + tid; i < end; i += 256) s += cnt[i];
#pragma unroll
    for (int d = 32; d > 0; d >>= 1) s += __shfl_down(s, d, 64);
    if ((tid & 63) == 0) wpart[tid >> 6] = s;
    __syncthreads();
    if (tid == 0) bsum[blockIdx.x] = wpart[0] + wpart[1] + wpart[2] + wpart[3];
}

__global__ void scan_bsum_k(int* __restrict__ bsum, int* __restrict__ off,
                            int nb, int n) {
    int lane = threadIdx.x;
    int orig = (lane < nb) ? bsum[lane] : 0;
    int incl = orig;
#pragma unroll
    for (int d = 1; d < 64; d <<= 1) {
        int t = __shfl_up(incl, d, 64);
        if (lane >= d) incl += t;
    }
    if (lane < nb) bsum[lane] = incl - orig;
    if (lane == 63) off[n] = incl;
}

__global__ __launch_bounds__(1024) void scan_blk_k(const int* __restrict__ cnt,
                                                   const int* __restrict__ bexcl,
                                                   int* __restrict__ off, int n) {
    __shared__ int wsum[16];
    const int tid = threadIdx.x, lane = tid & 63, wid = tid >> 6;
    int idx0 = blockIdx.x * SCHUNK + tid * 4;
    int v[4]; int s = 0;
#pragma unroll
    for (int j = 0; j < 4; ++j) { v[j] = (idx0 + j < n) ? cnt[idx0 + j] : 0; s += v[j]; }
    int sc = s;
#pragma unroll
    for (int d = 1; d < 64; d <<= 1) {
        int t = __shfl_up(sc, d, 64);
        if (lane >= d) sc += t;
    }
    if (lane == 63) wsum[wid] = sc;
    __syncthreads();
    if (wid == 0) {
        int ws = (lane < 16) ? wsum[lane] : 0;
#pragma unroll
        for (int d = 1; d < 16; d <<= 1) {
            int t = __shfl_up(ws, d, 64);
            if (lane >= d) ws += t;
        }
        if (lane < 16) wsum[lane] = ws;
    }
    __syncthreads();
    int wave_off = (wid > 0) ? wsum[wid - 1] : 0;
    int excl = bexcl[blockIdx.x] + wave_off + sc - s;
#pragma unroll
    for (int j = 0; j < 4; ++j) {
        if (idx0 + j < n) off[idx0 + j] = excl;
        excl += v[j];
    }
}

// ---------------- CSR gather: out[i] = sum_e attr[e] * in[src[e]] ----------------
template<bool IN_BF16, bool OUT_BF16>
__global__ __launch_bounds__(256) void gather_k(
    const void* __restrict__ in_, const int* __restrict__ off,
    const int2* __restrict__ ep, void* __restrict__ out_, int n) {
    int node = blockIdx.x * 4 + (threadIdx.x >> 6);
    if (node >= n) return;
    int lane = threadIdx.x & 63;
    int e0 = off[node], e1 = off[node + 1];
    float ax = 0.f, ay = 0.f;
    const unsigned int* inb = (const unsigned int*)in_;
    const float2* inf = (const float2*)in_;

    int e = e0;
    for (; e + 3 < e1; e += 4) {
        int2 p0 = ep[e], p1 = ep[e + 1], p2 = ep[e + 2], p3 = ep[e + 3];
        if (IN_BF16) {
            unsigned int v0 = inb[(size_t)p0.x * 64 + lane];
            unsigned int v1 = inb[(size_t)p1.x * 64 + lane];
            unsigned int v2 = inb[(size_t)p2.x * 64 + lane];
            unsigned int v3 = inb[(size_t)p3.x * 64 + lane];
            float a0 = __int_as_float(p0.y), a1 = __int_as_float(p1.y);
            float a2 = __int_as_float(p2.y), a3 = __int_as_float(p3.y);
            ax = fmaf(a0, bflo(v0), ax); ay = fmaf(a0, bfhi(v0), ay);
            ax = fmaf(a1, bflo(v1), ax); ay = fmaf(a1, bfhi(v1), ay);
            ax = fmaf(a2, bflo(v2), ax); ay = fmaf(a2, bfhi(v2), ay);
            ax = fmaf(a3, bflo(v3), ax); ay = fmaf(a3, bfhi(v3), ay);
        } else {
            float2 v0 = inf[(size_t)p0.x * 64 + lane];
            float2 v1 = inf[(size_t)p1.x * 64 + lane];
            float2 v2 = inf[(size_t)p2.x * 64 + lane];
            float2 v3 = inf[(size_t)p3.x * 64 + lane];
            float a0 = __int_as_float(p0.y), a1 = __int_as_float(p1.y);
            float a2 = __int_as_float(p2.y), a3 = __int_as_float(p3.y);
            ax = fmaf(a0, v0.x, ax); ay = fmaf(a0, v0.y, ay);
            ax = fmaf(a1, v1.x, ax); ay = fmaf(a1, v1.y, ay);
            ax = fmaf(a2, v2.x, ax); ay = fmaf(a2, v2.y, ay);
            ax = fmaf(a3, v3.x, ax); ay = fmaf(a3, v3.y, ay);
        }
    }
    for (; e < e1; ++e) {
        int2 p0 = ep[e];
        float a0 = __int_as_float(p0.y);
        if (IN_BF16) {
            unsigned int v0 = inb[(size_t)p0.x * 64 + lane];
            ax = fmaf(a0, bflo(v0), ax); ay = fmaf(a0, bfhi(v0), ay);
        } else {
            float2 v0 = inf[(size_t)p0.x * 64 + lane];
            ax = fmaf(a0, v0.x, ax); ay = fmaf(a0, v0.y, ay);
        }
    }

    if (OUT_BF16) {
        unsigned int lo = f2bf(ax), hi = f2bf(ay);
        ((unsigned int*)out_)[(size_t)node * 64 + lane] = lo | (hi << 16);
    } else {
        ((float2*)out_)[(size_t)node * 64 + lane] = make_float2(ax, ay);
    }
}

// ---------------- weight prep for ALL 4 layers: Wt[l][col][k] bf16 ----------------
__global__ __launch_bounds__(256) void wprep4_k(
    const float* __restrict__ w0s, const float* __restrict__ w0n,
    const float* __restrict__ w1s, const float* __restrict__ w1n,
    const float* __restrict__ w2s, const float* __restrict__ w2n,
    const float* __restrict__ w3s, const float* __restrict__ w3n,
    unsigned short* __restrict__ wt) {
    int i = blockIdx.x * blockDim.x + threadIdx.x;
    if (i >= 4 * 128 * 256) return;
    int l = i >> 15;
    int r = i & 32767;
    int col = r >> 8, k = r & 255;
    const float* ws = (l == 0) ? w0s : (l == 1) ? w1s : (l == 2) ? w2s : w3s;
    const float* wn = (l == 0) ? w0n : (l == 1) ? w1n : (l == 2) ? w2n : w3n;
    float v = (k < 128) ? ws[k * 128 + col] : wn[(k - 128) * 128 + col];
    wt[i] = f2bf(v);
}

// ---------------- MFMA conv: hout = relu(hin@Ws + agg@Wn + b), all bf16 ----------------
__global__ __launch_bounds__(256, 2) void conv_mfma_k(
    const unsigned short* __restrict__ hin, const unsigned short* __restrict__ agg,
    const unsigned short* __restrict__ wt, const float* __restrict__ bias,
    unsigned short* __restrict__ hout, int n) {
    const int wv = threadIdx.x >> 6;
    const int lane = threadIdx.x & 63;
    const int col0 = wv * 32;
    const int r0 = blockIdx.x * 64;
    if (r0 >= n) return;
    const int q = lane >> 4;
    const int lr = lane & 15;

    bf16x8 bfr[2][8];
#pragma unroll
    for (int nt = 0; nt < 2; ++nt) {
        int col = col0 + nt * 16 + lr;
#pragma unroll
        for (int kk = 0; kk < 8; ++kk)
            bfr[nt][kk] = *(const bf16x8*)(wt + col * 256 + kk * 32 + q * 8);
    }

    f32x4 acc[4][2];
#pragma unroll
    for (int m = 0; m < 4; ++m)
#pragma unroll
        for (int nt = 0; nt < 2; ++nt) acc[m][nt] = (f32x4)(0.f);

    int rowb[4];
#pragma unroll
    for (int m = 0; m < 4; ++m) {
        int row = r0 + m * 16 + lr;
        rowb[m] = (row < n) ? row : (n - 1);
    }

#pragma unroll
    for (int kk = 0; kk < 8; ++kk) {
        const unsigned short* srcbase = (kk < 4) ? hin : agg;
        const int koff = (kk & 3) * 32 + q * 8;
#pragma unroll
        for (int m = 0; m < 4; ++m) {
            bf16x8 a = *(const bf16x8*)(srcbase + (size_t)rowb[m] * C + koff);
#pragma unroll
            for (int nt = 0; nt < 2; ++nt)
                acc[m][nt] = __builtin_amdgcn_mfma_f32_16x16x32_bf16(
                    a, bfr[nt][kk], acc[m][nt], 0, 0, 0);
        }
    }

#pragma unroll
    for (int nt = 0; nt < 2; ++nt) {
        int col = col0 + nt * 16 + lr;
        float bv = bias[col];
#pragma unroll
        for (int m = 0; m < 4; ++m) {
#pragma unroll
            for (int r = 0; r < 4; ++r) {
                int row = r0 + m * 16 + q * 4 + r;
                if (row < n) {
                    float v = acc[m][nt][r] + bv;
                    hout[(size_t)row * C + col] = f2bf(v > 0.f ? v : 0.f);
                }
            }
        }
    }
}

// ---------------- launch ----------------

extern "C" void kernel_launch(void* const* d_in, const int* in_sizes, int n_in,
                              void* d_out, int out_size, void* d_ws, size_t ws_size,
                              hipStream_t stream) {
    const float* x         = (const float*)d_in[0];
    const int*   pool_src  = (const int*)d_in[1];
    const int*   pool_dst  = (const int*)d_in[2];
    const float* pool_attr = (const float*)d_in[3];
    const int*   pp_src    = (const int*)d_in[4];
    const int*   pp_dst    = (const int*)d_in[5];
    const float* pp_attr   = (const float*)d_in[6];
    const int*   up_src    = (const int*)d_in[7];
    const int*   up_dst    = (const int*)d_in[8];
    const float* up_attr   = (const float*)d_in[9];
    const float* w[12];
    for (int i = 0; i < 12; ++i) w[i] = (const float*)d_in[10 + i];

    const int E_pool = in_sizes[1];
    const int E_pp   = in_sizes[4];
    const int E_up   = in_sizes[7];
    const int NF     = in_sizes[0] / C;  // 100000
    const int TOT    = 2 * NC + NF;      // concatenated count length
    const int TE     = E_pool + E_pp + E_up;

    // workspace layout
    unsigned short* h   = (unsigned short*)d_ws;         // NC*C bf16
    unsigned short* h2  = h + (size_t)NC * C;            // NC*C bf16
    unsigned short* agg = h2 + (size_t)NC * C;           // NC*C bf16
    int*  cnt_all = (int*)(agg + (size_t)NC * C);        // TOT (cnt) ...
    int*  cur_all = cnt_all + TOT;                       // ... + TOT (cur), one memset
    int*  off_all = cur_all + TOT;                       // TOT+1
    int2* ep_all  = (int2*)(off_all + TOT + 1);          // TE
    unsigned short* wt = (unsigned short*)(ep_all + TE); // 4*128*256 bf16
    int* bsum = (int*)(wt + 4 * 128 * 256);              // 64 ints

    const int* pl_off = off_all;
    const int* pp_off = off_all + NC;
    const int* up_off = off_all + 2 * NC;

    const int TB = 256;

    // ---- weight prep (1 dispatch) ----
    wprep4_k<<<(4 * 128 * 256 + TB - 1) / TB, TB, 0, stream>>>(
        w[0], w[1], w[3], w[4], w[6], w[7], w[9], w[10], wt);

    // ---- fused CSR build (memset + hist + 3-step scan + fill = 6 dispatches) ----
    hipMemsetAsync(cnt_all, 0, 2 * (size_t)TOT * sizeof(int), stream);
    hist3_k<<<(TE + TB - 1) / TB, TB, 0, stream>>>(
        pool_dst, pp_dst, up_dst, cnt_all, E_pool, E_pp, E_up);
    {
        int nb = (TOT + SCHUNK - 1) / SCHUNK;  // 37
        reduce_k<<<nb, 256, 0, stream>>>(cnt_all, bsum, TOT);
        scan_bsum_k<<<1, 64, 0, stream>>>(bsum, off_all, nb, TOT);
        scan_blk_k<<<nb, 1024, 0, stream>>>(cnt_all, bsum, off_all, TOT);
    }
    fill3_k<<<(TE + TB - 1) / TB, TB, 0, stream>>>(
        pool_src, pool_attr, pp_src, pp_attr, up_src, up_attr,
        pool_dst, pp_dst, up_dst, off_all, cur_all, ep_all, E_pool, E_pp, E_up);

    // ---- compute chain ----
    gather_k<false, true><<<(NC + 3) / 4, 256, 0, stream>>>(x, pl_off, ep_all, h, NC);

    unsigned short* hcur = h;
    unsigned short* halt = h2;
    const int mtiles = (NC + 63) / 64;
    for (int l = 0; l < 4; ++l) {
        gather_k<true, true><<<(NC + 3) / 4, 256, 0, stream>>>(hcur, pp_off, ep_all, agg, NC);
        conv_mfma_k<<<mtiles, 256, 0, stream>>>(
            hcur, agg, wt + (size_t)l * 128 * 256, w[3 * l + 2], halt, NC);
        unsigned short* t = hcur; hcur = halt; halt = t;
    }

    gather_k<true, false><<<(NF + 3) / 4, 256, 0, stream>>>(hcur, up_off, ep_all, (float*)d_out, NF);
}

// Round 7
// 217.926 us; speedup vs baseline: 4.8993x; 1.2525x over previous
//
#include <hip/hip_runtime.h>
#include <hip/hip_bf16.h>

#define C 128
#define NC 25000
#define SCHUNK 4096

typedef __attribute__((ext_vector_type(8))) short bf16x8;
typedef __attribute__((ext_vector_type(4))) float f32x4;

static __device__ __forceinline__ unsigned short f2bf(float x) {
    __hip_bfloat16 h = __float2bfloat16(x);
    return __builtin_bit_cast(unsigned short, h);
}
static __device__ __forceinline__ float bflo(unsigned int v) {
    return __builtin_bit_cast(float, v << 16);
}
static __device__ __forceinline__ float bfhi(unsigned int v) {
    return __builtin_bit_cast(float, v & 0xffff0000u);
}

// ---------------- fused CSR build over 3 concatenated graphs ----------------
// cnt layout: [pool: 0..NC) [pp: NC..2NC) [up: 2NC..2NC+NF)
// Pass 1 (hist_rank): per-edge rank via atomicAdd (store-only, no dependent use).
// Pass 2 (fill2): slot = off[cidx] + rank[i], NO atomics.

__global__ __launch_bounds__(256) void hist_rank_k(
    const int* __restrict__ pl_dst, const int* __restrict__ pp_dst,
    const int* __restrict__ up_dst, int* __restrict__ cnt,
    int* __restrict__ rank, int Epl, int Epp, int Eup) {
    int i = blockIdx.x * blockDim.x + threadIdx.x;
    int cidx;
    if (i < Epl) {
        cidx = pl_dst[i];
    } else if (i < Epl + Epp) {
        cidx = NC + pp_dst[i - Epl];
    } else if (i < Epl + Epp + Eup) {
        cidx = 2 * NC + up_dst[i - Epl - Epp];
    } else return;
    rank[i] = atomicAdd(&cnt[cidx], 1);
}

__global__ __launch_bounds__(256) void fill2_k(
    const int* __restrict__ pl_src, const float* __restrict__ pl_attr,
    const int* __restrict__ pp_src, const float* __restrict__ pp_attr,
    const int* __restrict__ up_src, const float* __restrict__ up_attr,
    const int* __restrict__ pl_dst, const int* __restrict__ pp_dst,
    const int* __restrict__ up_dst,
    const int* __restrict__ off, const int* __restrict__ rank,
    int2* __restrict__ ep, int Epl, int Epp, int Eup) {
    int i = blockIdx.x * blockDim.x + threadIdx.x;
    int cidx, s; float a;
    if (i < Epl) {
        cidx = pl_dst[i]; s = pl_src[i]; a = pl_attr[i];
    } else if (i < Epl + Epp) {
        int j = i - Epl;
        cidx = NC + pp_dst[j]; s = pp_src[j]; a = pp_attr[j];
    } else if (i < Epl + Epp + Eup) {
        int j = i - Epl - Epp;
        cidx = 2 * NC + up_dst[j]; s = up_src[j]; a = up_attr[j];
    } else return;
    ep[off[cidx] + rank[i]] = make_int2(s, __float_as_int(a));
}

// ---------------- hierarchical scan (3 dispatches, parallel chunks) ----------------

__global__ __launch_bounds__(256) void reduce_k(const int* __restrict__ cnt,
                                                int* __restrict__ bsum, int n) {
    __shared__ int wpart[4];
    int base = blockIdx.x * SCHUNK;
    int tid = threadIdx.x;
    int end = base + SCHUNK; if (end > n) end = n;
    int s = 0;
    for (int i = base + tid; i < end; i += 256) s += cnt[i];
#pragma unroll
    for (int d = 32; d > 0; d >>= 1) s += __shfl_down(s, d, 64);
    if ((tid & 63) == 0) wpart[tid >> 6] = s;
    __syncthreads();
    if (tid == 0) bsum[blockIdx.x] = wpart[0] + wpart[1] + wpart[2] + wpart[3];
}

__global__ void scan_bsum_k(int* __restrict__ bsum, int* __restrict__ off,
                            int nb, int n) {
    int lane = threadIdx.x;
    int orig = (lane < nb) ? bsum[lane] : 0;
    int incl = orig;
#pragma unroll
    for (int d = 1; d < 64; d <<= 1) {
        int t = __shfl_up(incl, d, 64);
        if (lane >= d) incl += t;
    }
    if (lane < nb) bsum[lane] = incl - orig;
    if (lane == 63) off[n] = incl;
}

__global__ __launch_bounds__(1024) void scan_blk_k(const int* __restrict__ cnt,
                                                   const int* __restrict__ bexcl,
                                                   int* __restrict__ off, int n) {
    __shared__ int wsum[16];
    const int tid = threadIdx.x, lane = tid & 63, wid = tid >> 6;
    int idx0 = blockIdx.x * SCHUNK + tid * 4;
    int v[4]; int s = 0;
#pragma unroll
    for (int j = 0; j < 4; ++j) { v[j] = (idx0 + j < n) ? cnt[idx0 + j] : 0; s += v[j]; }
    int sc = s;
#pragma unroll
    for (int d = 1; d < 64; d <<= 1) {
        int t = __shfl_up(sc, d, 64);
        if (lane >= d) sc += t;
    }
    if (lane == 63) wsum[wid] = sc;
    __syncthreads();
    if (wid == 0) {
        int ws = (lane < 16) ? wsum[lane] : 0;
#pragma unroll
        for (int d = 1; d < 16; d <<= 1) {
            int t = __shfl_up(ws, d, 64);
            if (lane >= d) ws += t;
        }
        if (lane < 16) wsum[lane] = ws;
    }
    __syncthreads();
    int wave_off = (wid > 0) ? wsum[wid - 1] : 0;
    int excl = bexcl[blockIdx.x] + wave_off + sc - s;
#pragma unroll
    for (int j = 0; j < 4; ++j) {
        if (idx0 + j < n) off[idx0 + j] = excl;
        excl += v[j];
    }
}

// ---------------- CSR gather, quarter-wave: 16 lanes/node, 16B/lane ----------------
// lane owns 8 channels (ch = lane*8 .. lane*8+7). One wave = 4 nodes.
template<bool IN_BF16, bool OUT_BF16>
__global__ __launch_bounds__(256) void gather_k(
    const void* __restrict__ in_, const int* __restrict__ off,
    const int2* __restrict__ ep, void* __restrict__ out_, int n) {
    int node = (blockIdx.x * 256 + threadIdx.x) >> 4;
    if (node >= n) return;
    int lane = threadIdx.x & 15;
    int e0 = off[node], e1 = off[node + 1];
    float acc[8];
#pragma unroll
    for (int j = 0; j < 8; ++j) acc[j] = 0.f;

    const unsigned int* inb = (const unsigned int*)in_;
    const float* inf = (const float*)in_;

    int e = e0;
    for (; e + 1 < e1; e += 2) {
        int2 p0 = ep[e], p1 = ep[e + 1];
        float a0 = __int_as_float(p0.y), a1 = __int_as_float(p1.y);
        if (IN_BF16) {
            uint4 v0 = *(const uint4*)(inb + (size_t)p0.x * 64 + lane * 4);
            uint4 v1 = *(const uint4*)(inb + (size_t)p1.x * 64 + lane * 4);
            acc[0] = fmaf(a0, bflo(v0.x), acc[0]); acc[1] = fmaf(a0, bfhi(v0.x), acc[1]);
            acc[2] = fmaf(a0, bflo(v0.y), acc[2]); acc[3] = fmaf(a0, bfhi(v0.y), acc[3]);
            acc[4] = fmaf(a0, bflo(v0.z), acc[4]); acc[5] = fmaf(a0, bfhi(v0.z), acc[5]);
            acc[6] = fmaf(a0, bflo(v0.w), acc[6]); acc[7] = fmaf(a0, bfhi(v0.w), acc[7]);
            acc[0] = fmaf(a1, bflo(v1.x), acc[0]); acc[1] = fmaf(a1, bfhi(v1.x), acc[1]);
            acc[2] = fmaf(a1, bflo(v1.y), acc[2]); acc[3] = fmaf(a1, bfhi(v1.y), acc[3]);
            acc[4] = fmaf(a1, bflo(v1.z), acc[4]); acc[5] = fmaf(a1, bfhi(v1.z), acc[5]);
            acc[6] = fmaf(a1, bflo(v1.w), acc[6]); acc[7] = fmaf(a1, bfhi(v1.w), acc[7]);
        } else {
            const float* r0 = inf + (size_t)p0.x * C + lane * 8;
            const float* r1 = inf + (size_t)p1.x * C + lane * 8;
            float4 u0 = *(const float4*)r0, u1 = *(const float4*)(r0 + 4);
            float4 w0 = *(const float4*)r1, w1 = *(const float4*)(r1 + 4);
            acc[0] = fmaf(a0, u0.x, acc[0]); acc[1] = fmaf(a0, u0.y, acc[1]);
            acc[2] = fmaf(a0, u0.z, acc[2]); acc[3] = fmaf(a0, u0.w, acc[3]);
            acc[4] = fmaf(a0, u1.x, acc[4]); acc[5] = fmaf(a0, u1.y, acc[5]);
            acc[6] = fmaf(a0, u1.z, acc[6]); acc[7] = fmaf(a0, u1.w, acc[7]);
            acc[0] = fmaf(a1, w0.x, acc[0]); acc[1] = fmaf(a1, w0.y, acc[1]);
            acc[2] = fmaf(a1, w0.z, acc[2]); acc[3] = fmaf(a1, w0.w, acc[3]);
            acc[4] = fmaf(a1, w1.x, acc[4]); acc[5] = fmaf(a1, w1.y, acc[5]);
            acc[6] = fmaf(a1, w1.z, acc[6]); acc[7] = fmaf(a1, w1.w, acc[7]);
        }
    }
    if (e < e1) {
        int2 p0 = ep[e];
        float a0 = __int_as_float(p0.y);
        if (IN_BF16) {
            uint4 v0 = *(const uint4*)(inb + (size_t)p0.x * 64 + lane * 4);
            acc[0] = fmaf(a0, bflo(v0.x), acc[0]); acc[1] = fmaf(a0, bfhi(v0.x), acc[1]);
            acc[2] = fmaf(a0, bflo(v0.y), acc[2]); acc[3] = fmaf(a0, bfhi(v0.y), acc[3]);
            acc[4] = fmaf(a0, bflo(v0.z), acc[4]); acc[5] = fmaf(a0, bfhi(v0.z), acc[5]);
            acc[6] = fmaf(a0, bflo(v0.w), acc[6]); acc[7] = fmaf(a0, bfhi(v0.w), acc[7]);
        } else {
            const float* r0 = inf + (size_t)p0.x * C + lane * 8;
            float4 u0 = *(const float4*)r0, u1 = *(const float4*)(r0 + 4);
            acc[0] = fmaf(a0, u0.x, acc[0]); acc[1] = fmaf(a0, u0.y, acc[1]);
            acc[2] = fmaf(a0, u0.z, acc[2]); acc[3] = fmaf(a0, u0.w, acc[3]);
            acc[4] = fmaf(a0, u1.x, acc[4]); acc[5] = fmaf(a0, u1.y, acc[5]);
            acc[6] = fmaf(a0, u1.z, acc[6]); acc[7] = fmaf(a0, u1.w, acc[7]);
        }
    }

    if (OUT_BF16) {
        uint4 r;
        r.x = (unsigned)f2bf(acc[0]) | ((unsigned)f2bf(acc[1]) << 16);
        r.y = (unsigned)f2bf(acc[2]) | ((unsigned)f2bf(acc[3]) << 16);
        r.z = (unsigned)f2bf(acc[4]) | ((unsigned)f2bf(acc[5]) << 16);
        r.w = (unsigned)f2bf(acc[6]) | ((unsigned)f2bf(acc[7]) << 16);
        *(uint4*)((unsigned int*)out_ + (size_t)node * 64 + lane * 4) = r;
    } else {
        float* ob = (float*)out_ + (size_t)node * C + lane * 8;
        *(float4*)ob = make_float4(acc[0], acc[1], acc[2], acc[3]);
        *(float4*)(ob + 4) = make_float4(acc[4], acc[5], acc[6], acc[7]);
    }
}

// ---------------- weight prep for ALL 4 layers: Wt[l][col][k] bf16 ----------------
__global__ __launch_bounds__(256) void wprep4_k(
    const float* __restrict__ w0s, const float* __restrict__ w0n,
    const float* __restrict__ w1s, const float* __restrict__ w1n,
    const float* __restrict__ w2s, const float* __restrict__ w2n,
    const float* __restrict__ w3s, const float* __restrict__ w3n,
    unsigned short* __restrict__ wt) {
    int i = blockIdx.x * blockDim.x + threadIdx.x;
    if (i >= 4 * 128 * 256) return;
    int l = i >> 15;
    int r = i & 32767;
    int col = r >> 8, k = r & 255;
    const float* ws = (l == 0) ? w0s : (l == 1) ? w1s : (l == 2) ? w2s : w3s;
    const float* wn = (l == 0) ? w0n : (l == 1) ? w1n : (l == 2) ? w2n : w3n;
    float v = (k < 128) ? ws[k * 128 + col] : wn[(k - 128) * 128 + col];
    wt[i] = f2bf(v);
}

// ---------------- MFMA conv: hout = relu(hin@Ws + agg@Wn + b), all bf16 ----------------
__global__ __launch_bounds__(256, 2) void conv_mfma_k(
    const unsigned short* __restrict__ hin, const unsigned short* __restrict__ agg,
    const unsigned short* __restrict__ wt, const float* __restrict__ bias,
    unsigned short* __restrict__ hout, int n) {
    const int wv = threadIdx.x >> 6;
    const int lane = threadIdx.x & 63;
    const int col0 = wv * 32;
    const int r0 = blockIdx.x * 64;
    if (r0 >= n) return;
    const int q = lane >> 4;
    const int lr = lane & 15;

    bf16x8 bfr[2][8];
#pragma unroll
    for (int nt = 0; nt < 2; ++nt) {
        int col = col0 + nt * 16 + lr;
#pragma unroll
        for (int kk = 0; kk < 8; ++kk)
            bfr[nt][kk] = *(const bf16x8*)(wt + col * 256 + kk * 32 + q * 8);
    }

    f32x4 acc[4][2];
#pragma unroll
    for (int m = 0; m < 4; ++m)
#pragma unroll
        for (int nt = 0; nt < 2; ++nt) acc[m][nt] = (f32x4)(0.f);

    int rowb[4];
#pragma unroll
    for (int m = 0; m < 4; ++m) {
        int row = r0 + m * 16 + lr;
        rowb[m] = (row < n) ? row : (n - 1);
    }

#pragma unroll
    for (int kk = 0; kk < 8; ++kk) {
        const unsigned short* srcbase = (kk < 4) ? hin : agg;
        const int koff = (kk & 3) * 32 + q * 8;
#pragma unroll
        for (int m = 0; m < 4; ++m) {
            bf16x8 a = *(const bf16x8*)(srcbase + (size_t)rowb[m] * C + koff);
#pragma unroll
            for (int nt = 0; nt < 2; ++nt)
                acc[m][nt] = __builtin_amdgcn_mfma_f32_16x16x32_bf16(
                    a, bfr[nt][kk], acc[m][nt], 0, 0, 0);
        }
    }

#pragma unroll
    for (int nt = 0; nt < 2; ++nt) {
        int col = col0 + nt * 16 + lr;
        float bv = bias[col];
#pragma unroll
        for (int m = 0; m < 4; ++m) {
#pragma unroll
            for (int r = 0; r < 4; ++r) {
                int row = r0 + m * 16 + q * 4 + r;
                if (row < n) {
                    float v = acc[m][nt][r] + bv;
                    hout[(size_t)row * C + col] = f2bf(v > 0.f ? v : 0.f);
                }
            }
        }
    }
}

// ---------------- launch ----------------

extern "C" void kernel_launch(void* const* d_in, const int* in_sizes, int n_in,
                              void* d_out, int out_size, void* d_ws, size_t ws_size,
                              hipStream_t stream) {
    const float* x         = (const float*)d_in[0];
    const int*   pool_src  = (const int*)d_in[1];
    const int*   pool_dst  = (const int*)d_in[2];
    const float* pool_attr = (const float*)d_in[3];
    const int*   pp_src    = (const int*)d_in[4];
    const int*   pp_dst    = (const int*)d_in[5];
    const float* pp_attr   = (const float*)d_in[6];
    const int*   up_src    = (const int*)d_in[7];
    const int*   up_dst    = (const int*)d_in[8];
    const float* up_attr   = (const float*)d_in[9];
    const float* w[12];
    for (int i = 0; i < 12; ++i) w[i] = (const float*)d_in[10 + i];

    const int E_pool = in_sizes[1];
    const int E_pp   = in_sizes[4];
    const int E_up   = in_sizes[7];
    const int NF     = in_sizes[0] / C;  // 100000
    const int TOT    = 2 * NC + NF;      // concatenated count length
    const int TE     = E_pool + E_pp + E_up;

    // workspace layout
    unsigned short* h   = (unsigned short*)d_ws;         // NC*C bf16
    unsigned short* h2  = h + (size_t)NC * C;            // NC*C bf16
    unsigned short* agg = h2 + (size_t)NC * C;           // NC*C bf16
    int*  cnt_all = (int*)(agg + (size_t)NC * C);        // TOT
    int*  off_all = cnt_all + TOT;                       // TOT+1
    int*  rank    = off_all + TOT + 1;                   // TE
    int2* ep_all  = (int2*)(rank + TE);                  // TE
    unsigned short* wt = (unsigned short*)(ep_all + TE); // 4*128*256 bf16
    int* bsum = (int*)(wt + 4 * 128 * 256);              // 64 ints

    const int* pl_off = off_all;
    const int* pp_off = off_all + NC;
    const int* up_off = off_all + 2 * NC;

    const int TB = 256;

    // ---- weight prep (1 dispatch) ----
    wprep4_k<<<(4 * 128 * 256 + TB - 1) / TB, TB, 0, stream>>>(
        w[0], w[1], w[3], w[4], w[6], w[7], w[9], w[10], wt);

    // ---- fused CSR build: memset + hist_rank + 3-step scan + atomic-free fill ----
    hipMemsetAsync(cnt_all, 0, (size_t)TOT * sizeof(int), stream);
    hist_rank_k<<<(TE + TB - 1) / TB, TB, 0, stream>>>(
        pool_dst, pp_dst, up_dst, cnt_all, rank, E_pool, E_pp, E_up);
    {
        int nb = (TOT + SCHUNK - 1) / SCHUNK;  // 37
        reduce_k<<<nb, 256, 0, stream>>>(cnt_all, bsum, TOT);
        scan_bsum_k<<<1, 64, 0, stream>>>(bsum, off_all, nb, TOT);
        scan_blk_k<<<nb, 1024, 0, stream>>>(cnt_all, bsum, off_all, TOT);
    }
    fill2_k<<<(TE + TB - 1) / TB, TB, 0, stream>>>(
        pool_src, pool_attr, pp_src, pp_attr, up_src, up_attr,
        pool_dst, pp_dst, up_dst, off_all, rank, ep_all, E_pool, E_pp, E_up);

    // ---- compute chain ----
    gather_k<false, true><<<((size_t)NC * 16 + 255) / 256, 256, 0, stream>>>(
        x, pl_off, ep_all, h, NC);

    unsigned short* hcur = h;
    unsigned short* halt = h2;
    const int mtiles = (NC + 63) / 64;
    for (int l = 0; l < 4; ++l) {
        gather_k<true, true><<<((size_t)NC * 16 + 255) / 256, 256, 0, stream>>>(
            hcur, pp_off, ep_all, agg, NC);
        conv_mfma_k<<<mtiles, 256, 0, stream>>>(
            hcur, agg, wt + (size_t)l * 128 * 256, w[3 * l + 2], halt, NC);
        unsigned short* t = hcur; hcur = halt; halt = t;
    }

    gather_k<true, false><<<((size_t)NF * 16 + 255) / 256, 256, 0, stream>>>(
        hcur, up_off, ep_all, (float*)d_out, NF);
}